// Round 1
// baseline (160.755 us; speedup 1.0000x reference)
//
#include <hip/hip_runtime.h>
#include <hip/hip_bf16.h>

#define HW 16384
#define WD 128

__global__ __launch_bounds__(256) void la_k1(
    const float* __restrict__ x,
    const float* __restrict__ w1, const float* __restrict__ b1,
    const float* __restrict__ g1, const float* __restrict__ be1,
    const float* __restrict__ m1, const float* __restrict__ v1,
    const float* __restrict__ w2, const float* __restrict__ b2,
    const float* __restrict__ g2, const float* __restrict__ be2,
    const float* __restrict__ m2, const float* __restrict__ v2,
    const float* __restrict__ wv,
    float* __restrict__ mn, float* __restrict__ vout)
{
    const int pix = blockIdx.x * blockDim.x + threadIdx.x;   // 0..HW-1
    const int bg  = blockIdx.y;                               // b*8+g
    const int b   = bg >> 3, g = bg & 7;

    // ---- load 32 x channels for this group/pixel ----
    const float* xp = x + (size_t)(b * 256 + g * 32) * HW + pix;
    float xg[32];
#pragma unroll
    for (int c = 0; c < 32; ++c) xg[c] = xp[(size_t)c * HW];

    // ---- t = tanh(bn(gconv1(x)+b1)) : 8 channels ----
    float t[8];
    const float* w1g = w1 + g * 256;           // (8 out, 32 in)
#pragma unroll
    for (int o = 0; o < 8; ++o) {
        float acc = 0.f;
#pragma unroll
        for (int ci = 0; ci < 32; ++ci) acc = fmaf(xg[ci], w1g[o * 32 + ci], acc);
        const int ch  = g * 8 + o;
        const float inv = g1[ch] * rsqrtf(v1[ch] + 1e-5f);
        const float add = be1[ch] + (b1[ch] - m1[ch]) * inv;
        t[o] = tanhf(fmaf(acc, inv, add));
    }

    // ---- mn = bn(gconv2(t)+b2) : 10 channels, write to ws ----
    const float* w2g = w2 + g * 80;            // (10 out, 8 in)
    float* mnp = mn + (size_t)(b * 80 + g * 10) * HW + pix;
#pragma unroll
    for (int o = 0; o < 10; ++o) {
        float acc = 0.f;
#pragma unroll
        for (int i = 0; i < 8; ++i) acc = fmaf(t[i], w2g[o * 8 + i], acc);
        const int ch  = g * 10 + o;
        const float inv = g2[ch] * rsqrtf(v2[ch] + 1e-5f);
        const float add = be2[ch] + (b2[ch] - m2[ch]) * inv;
        mnp[(size_t)o * HW] = fmaf(acc, inv, add);
    }

    // ---- v = gconv(x, wv) : 32 channels, write to ws ----
    const float* wvg = wv + g * 1024;          // (32 out, 32 in)
    float* vp = vout + (size_t)(b * 256 + g * 32) * HW + pix;
#pragma unroll 4
    for (int o = 0; o < 32; ++o) {
        float acc = 0.f;
#pragma unroll
        for (int ci = 0; ci < 32; ++ci) acc = fmaf(xg[ci], wvg[o * 32 + ci], acc);
        vp[(size_t)o * HW] = acc;
    }
}

__global__ __launch_bounds__(256) void la_k2(
    const float* __restrict__ mn, const float* __restrict__ v,
    float* __restrict__ out)
{
    const int pix = blockIdx.x * blockDim.x + threadIdx.x;
    const int bg  = blockIdx.y;
    const int b   = bg >> 3, g = bg & 7;
    const int h   = pix >> 7, w = pix & 127;

    const float* nbch  = mn + (size_t)(b * 80 + g) * HW;                 // neighbor channel g
    const float* maskp = mn + (size_t)(b * 80 + 8 + g * 9) * HW + pix;   // mask channels

    // logits = mask(center) + neighbor(tap), zero-padded neighbor
    float logit[9];
    int   off[9];
    bool  ok[9];
#pragma unroll
    for (int k = 0; k < 9; ++k) {
        const int hh = h + k / 3 - 1;
        const int ww = w + k % 3 - 1;
        ok[k]  = ((unsigned)hh < 128u) && ((unsigned)ww < 128u);
        off[k] = ok[k] ? hh * WD + ww : 0;
        const float nb = ok[k] ? nbch[off[k]] : 0.f;
        logit[k] = maskp[(size_t)k * HW] + nb;
    }

    float mx = logit[0];
#pragma unroll
    for (int k = 1; k < 9; ++k) mx = fmaxf(mx, logit[k]);

    float wsum = 0.f;
    float wsel[9];
#pragma unroll
    for (int k = 0; k < 9; ++k) {
        const float e = __expf(logit[k] - mx);
        wsum += e;                    // denominator includes padded taps
        wsel[k] = ok[k] ? e : 0.f;    // padded taps contribute zero v
    }
    const float rs = 1.f / wsum;

    const float* vg = v   + (size_t)(b * 256 + g * 32) * HW;
    float*       og = out + (size_t)(b * 256 + g * 32) * HW + pix;
#pragma unroll 4
    for (int o = 0; o < 32; ++o) {
        const float* vo = vg + (size_t)o * HW;
        float acc = 0.f;
#pragma unroll
        for (int k = 0; k < 9; ++k) acc = fmaf(wsel[k], vo[off[k]], acc);
        og[(size_t)o * HW] = acc * rs;
    }
}

extern "C" void kernel_launch(void* const* d_in, const int* in_sizes, int n_in,
                              void* d_out, int out_size, void* d_ws, size_t ws_size,
                              hipStream_t stream)
{
    const float* x   = (const float*)d_in[0];
    const float* w1  = (const float*)d_in[1];
    const float* b1  = (const float*)d_in[2];
    const float* g1  = (const float*)d_in[3];
    const float* be1 = (const float*)d_in[4];
    const float* m1  = (const float*)d_in[5];
    const float* v1  = (const float*)d_in[6];
    const float* w2  = (const float*)d_in[7];
    const float* b2  = (const float*)d_in[8];
    const float* g2  = (const float*)d_in[9];
    const float* be2 = (const float*)d_in[10];
    const float* m2  = (const float*)d_in[11];
    const float* v2  = (const float*)d_in[12];
    const float* wv  = (const float*)d_in[13];

    float* out = (float*)d_out;
    float* mn  = (float*)d_ws;                       // 2*80*16384 floats = 10.5 MB
    float* v   = mn + (size_t)2 * 80 * HW;           // 2*256*16384 floats = 33.5 MB

    dim3 blk(256);
    dim3 grid(HW / 256, 16);                         // (64 pixel-blocks, b*G+g)

    hipLaunchKernelGGL(la_k1, grid, blk, 0, stream,
                       x, w1, b1, g1, be1, m1, v1, w2, b2, g2, be2, m2, v2, wv,
                       mn, v);
    hipLaunchKernelGGL(la_k2, grid, blk, 0, stream, mn, v, out);
}

// Round 2
// 153.618 us; speedup vs baseline: 1.0465x; 1.0465x over previous
//
#include <hip/hip_runtime.h>
#include <hip/hip_bf16.h>

#define HW  16384
#define WD  128
#define MNS (HW + 64)   // padded channel stride for mn workspace
#define VS  (HW + 64)   // padded channel stride for v workspace

// ---------------- k1: x -> mn (10ch/group), v (32ch/group) ; 2 px/thread ----
__global__ __launch_bounds__(256) void la_k1(
    const float* __restrict__ x,
    const float* __restrict__ w1, const float* __restrict__ b1,
    const float* __restrict__ g1, const float* __restrict__ be1,
    const float* __restrict__ m1, const float* __restrict__ v1,
    const float* __restrict__ w2, const float* __restrict__ b2,
    const float* __restrict__ g2, const float* __restrict__ be2,
    const float* __restrict__ m2, const float* __restrict__ v2,
    const float* __restrict__ wv,
    float* __restrict__ mn, float* __restrict__ vout)
{
    const int pix2 = (blockIdx.x * blockDim.x + threadIdx.x) * 2;  // 0..16382
    const int bg   = blockIdx.y;
    const int b    = bg >> 3, g = bg & 7;

    const float* xp = x + (size_t)(b * 256 + g * 32) * HW + pix2;
    float2 xg[32];
#pragma unroll
    for (int c = 0; c < 32; ++c)
        xg[c] = *(const float2*)(xp + (size_t)c * HW);

    // t = tanh(bn(gconv1(x)+b1))
    float2 t[8];
    const float* w1g = w1 + g * 256;
#pragma unroll
    for (int o = 0; o < 8; ++o) {
        float ax = 0.f, ay = 0.f;
#pragma unroll
        for (int ci = 0; ci < 32; ++ci) {
            const float w = w1g[o * 32 + ci];
            ax = fmaf(xg[ci].x, w, ax);
            ay = fmaf(xg[ci].y, w, ay);
        }
        const int ch = g * 8 + o;
        const float inv = g1[ch] * rsqrtf(v1[ch] + 1e-5f);
        const float add = be1[ch] + (b1[ch] - m1[ch]) * inv;
        t[o].x = tanhf(fmaf(ax, inv, add));
        t[o].y = tanhf(fmaf(ay, inv, add));
    }

    // mn = bn(gconv2(t)+b2), 10 channels
    const float* w2g = w2 + g * 80;
    float* mnp = mn + (size_t)(b * 80 + g * 10) * MNS + pix2;
#pragma unroll
    for (int o = 0; o < 10; ++o) {
        float ax = 0.f, ay = 0.f;
#pragma unroll
        for (int i = 0; i < 8; ++i) {
            const float w = w2g[o * 8 + i];
            ax = fmaf(t[i].x, w, ax);
            ay = fmaf(t[i].y, w, ay);
        }
        const int ch = g * 10 + o;
        const float inv = g2[ch] * rsqrtf(v2[ch] + 1e-5f);
        const float add = be2[ch] + (b2[ch] - m2[ch]) * inv;
        *(float2*)(mnp + (size_t)o * MNS) = make_float2(fmaf(ax, inv, add), fmaf(ay, inv, add));
    }

    // v = gconv(x, wv), 32 channels
    const float* wvg = wv + g * 1024;
    float* vp = vout + (size_t)(b * 256 + g * 32) * VS + pix2;
#pragma unroll 4
    for (int o = 0; o < 32; ++o) {
        float ax = 0.f, ay = 0.f;
#pragma unroll
        for (int ci = 0; ci < 32; ++ci) {
            const float w = wvg[o * 32 + ci];
            ax = fmaf(xg[ci].x, w, ax);
            ay = fmaf(xg[ci].y, w, ay);
        }
        *(float2*)(vp + (size_t)o * VS) = make_float2(ax, ay);
    }
}

// ---------------- k2: softmax attention + 9-tap gather ; 4 px/thread --------
__global__ __launch_bounds__(256) void la_k2(
    const float* __restrict__ mn, const float* __restrict__ v,
    float* __restrict__ out)
{
    const int q  = blockIdx.x * blockDim.x + threadIdx.x;  // quad index 0..4095
    const int p4 = q * 4;
    const int bg = blockIdx.y;
    const int b  = bg >> 3, g = bg & 7;
    const int h  = p4 >> 7, w0 = p4 & 127;                 // w0 in {0,4,...,124}

    // row offsets (clamped; out-of-range taps are masked below)
    int rofs[3];
    bool rok[3];
#pragma unroll
    for (int di = 0; di < 3; ++di) {
        const int hh = h + di - 1;
        rok[di]  = ((unsigned)hh < 128u);
        rofs[di] = (rok[di] ? hh : h) * WD;
    }
    const bool lok = (w0 > 0);        // col w0-1 valid
    const bool rvk = (w0 + 4 < 128);  // col w0+4 valid
    const int  lc  = lok ? (w0 - 1) : w0;
    const int  rc  = rvk ? (w0 + 4) : (w0 + 3);

    // ---- neighbor rows: 6 values per row ----
    const float* nbch = mn + (size_t)(b * 80 + g) * MNS;
    float nrv[3][6];
#pragma unroll
    for (int di = 0; di < 3; ++di) {
        const float* rp = nbch + rofs[di];
        const float4 f4 = *(const float4*)(rp + w0);
        nrv[di][0] = (rok[di] && lok) ? rp[lc] : 0.f;
        nrv[di][1] = rok[di] ? f4.x : 0.f;
        nrv[di][2] = rok[di] ? f4.y : 0.f;
        nrv[di][3] = rok[di] ? f4.z : 0.f;
        nrv[di][4] = rok[di] ? f4.w : 0.f;
        nrv[di][5] = (rok[di] && rvk) ? rp[rc] : 0.f;
    }

    // ---- logits & softmax for 4 pixels ----
    const float* maskp = mn + (size_t)(b * 80 + 8 + g * 9) * MNS + p4;
    float wsel[4][9];
    float mx[4] = {-1e30f, -1e30f, -1e30f, -1e30f};
#pragma unroll
    for (int k = 0; k < 9; ++k) {
        const int di = k / 3, dj = k % 3;      // dj: 0->-1,1->0,2->+1 (index j+dj)
        const float4 mk = *(const float4*)(maskp + (size_t)k * MNS);
        const float m0 = mk.x, m1_ = mk.y, m2_ = mk.z, m3 = mk.w;
        wsel[0][k] = m0  + nrv[di][0 + dj];
        wsel[1][k] = m1_ + nrv[di][1 + dj];
        wsel[2][k] = m2_ + nrv[di][2 + dj];
        wsel[3][k] = m3  + nrv[di][3 + dj];
#pragma unroll
        for (int j = 0; j < 4; ++j) mx[j] = fmaxf(mx[j], wsel[j][k]);
    }
    float rs[4];
#pragma unroll
    for (int j = 0; j < 4; ++j) {
        float s = 0.f;
#pragma unroll
        for (int k = 0; k < 9; ++k) {
            const float e = __expf(wsel[j][k] - mx[j]);
            s += e;
            // zero weight where the tap is out of image (numerator only)
            const int di = k / 3, dj = k % 3;
            const int col = w0 + j + dj - 1;
            const bool ok = rok[di] && ((unsigned)col < 128u);
            wsel[j][k] = ok ? e : 0.f;
        }
        rs[j] = 1.f / s;
#pragma unroll
        for (int k = 0; k < 9; ++k) wsel[j][k] *= rs[j];
    }

    // ---- 16 v-channels for this z-half ----
    const int o0 = blockIdx.z * 16;
    const float* vg = v   + (size_t)(b * 256 + g * 32 + o0) * VS;
    float*       og = out + (size_t)(b * 256 + g * 32 + o0) * HW + p4;
#pragma unroll 2
    for (int o = 0; o < 16; ++o) {
        const float* vo = vg + (size_t)o * VS;
        float vrv[3][6];
#pragma unroll
        for (int di = 0; di < 3; ++di) {
            const float* rp = vo + rofs[di];
            const float4 f4 = *(const float4*)(rp + w0);
            vrv[di][0] = rp[lc];
            vrv[di][1] = f4.x; vrv[di][2] = f4.y; vrv[di][3] = f4.z; vrv[di][4] = f4.w;
            vrv[di][5] = rp[rc];
        }
        float acc[4] = {0.f, 0.f, 0.f, 0.f};
#pragma unroll
        for (int k = 0; k < 9; ++k) {
            const int di = k / 3, dj = k % 3;
#pragma unroll
            for (int j = 0; j < 4; ++j)
                acc[j] = fmaf(wsel[j][k], vrv[di][j + dj], acc[j]);
        }
        *(float4*)(og + (size_t)o * HW) = make_float4(acc[0], acc[1], acc[2], acc[3]);
    }
}

extern "C" void kernel_launch(void* const* d_in, const int* in_sizes, int n_in,
                              void* d_out, int out_size, void* d_ws, size_t ws_size,
                              hipStream_t stream)
{
    const float* x   = (const float*)d_in[0];
    const float* w1  = (const float*)d_in[1];
    const float* b1  = (const float*)d_in[2];
    const float* g1  = (const float*)d_in[3];
    const float* be1 = (const float*)d_in[4];
    const float* m1  = (const float*)d_in[5];
    const float* v1  = (const float*)d_in[6];
    const float* w2  = (const float*)d_in[7];
    const float* b2  = (const float*)d_in[8];
    const float* g2  = (const float*)d_in[9];
    const float* be2 = (const float*)d_in[10];
    const float* m2  = (const float*)d_in[11];
    const float* v2  = (const float*)d_in[12];
    const float* wv  = (const float*)d_in[13];

    float* out = (float*)d_out;
    float* mn  = (float*)d_ws;                         // 2*80*MNS floats
    float* v   = mn + (size_t)2 * 80 * MNS;            // 2*256*MNS floats

    dim3 blk(256);
    dim3 g1d(HW / 512, 16);        // k1: 2 px/thread -> (32, 16) = 512 blocks
    dim3 g2d(HW / 1024, 16, 2);    // k2: 4 px/thread, 2-way ch split -> 512 blocks

    hipLaunchKernelGGL(la_k1, g1d, blk, 0, stream,
                       x, w1, b1, g1, be1, m1, v1, w2, b2, g2, be2, m2, v2, wv,
                       mn, v);
    hipLaunchKernelGGL(la_k2, g2d, blk, 0, stream, mn, v, out);
}

// Round 3
// 151.147 us; speedup vs baseline: 1.0636x; 1.0164x over previous
//
#include <hip/hip_runtime.h>
#include <hip/hip_bf16.h>

#define HW  16384
#define WD  128
#define MNS (HW + 64)   // padded channel stride for mn workspace
#define VS  (HW + 64)   // padded channel stride for v workspace

// ---- k1: x -> mn (10ch/group, z==0), v (16ch per z) ; 2 px/thread ----------
__global__ __launch_bounds__(256) void la_k1(
    const float* __restrict__ x,
    const float* __restrict__ w1, const float* __restrict__ b1,
    const float* __restrict__ g1, const float* __restrict__ be1,
    const float* __restrict__ m1, const float* __restrict__ v1,
    const float* __restrict__ w2, const float* __restrict__ b2,
    const float* __restrict__ g2, const float* __restrict__ be2,
    const float* __restrict__ m2, const float* __restrict__ v2,
    const float* __restrict__ wv,
    float* __restrict__ mn, float* __restrict__ vout)
{
    const int pix2 = (blockIdx.x * blockDim.x + threadIdx.x) * 2;  // 0..16382
    const int bg   = blockIdx.y;
    const int b    = bg >> 3, g = bg & 7;
    const int z    = blockIdx.z;          // 0: t+mn+v[0:16], 1: v[16:32]

    const float* xp = x + (size_t)(b * 256 + g * 32) * HW + pix2;
    float2 xg[32];
#pragma unroll
    for (int c = 0; c < 32; ++c)
        xg[c] = *(const float2*)(xp + (size_t)c * HW);

    if (z == 0) {
        // t = tanh(bn(gconv1(x)+b1))
        float2 t[8];
        const float* w1g = w1 + g * 256;
#pragma unroll
        for (int o = 0; o < 8; ++o) {
            float ax = 0.f, ay = 0.f;
#pragma unroll
            for (int ci = 0; ci < 32; ++ci) {
                const float w = w1g[o * 32 + ci];
                ax = fmaf(xg[ci].x, w, ax);
                ay = fmaf(xg[ci].y, w, ay);
            }
            const int ch = g * 8 + o;
            const float inv = g1[ch] * rsqrtf(v1[ch] + 1e-5f);
            const float add = be1[ch] + (b1[ch] - m1[ch]) * inv;
            t[o].x = tanhf(fmaf(ax, inv, add));
            t[o].y = tanhf(fmaf(ay, inv, add));
        }

        // mn = bn(gconv2(t)+b2), 10 channels
        const float* w2g = w2 + g * 80;
        float* mnp = mn + (size_t)(b * 80 + g * 10) * MNS + pix2;
#pragma unroll
        for (int o = 0; o < 10; ++o) {
            float ax = 0.f, ay = 0.f;
#pragma unroll
            for (int i = 0; i < 8; ++i) {
                const float w = w2g[o * 8 + i];
                ax = fmaf(t[i].x, w, ax);
                ay = fmaf(t[i].y, w, ay);
            }
            const int ch = g * 10 + o;
            const float inv = g2[ch] * rsqrtf(v2[ch] + 1e-5f);
            const float add = be2[ch] + (b2[ch] - m2[ch]) * inv;
            *(float2*)(mnp + (size_t)o * MNS) =
                make_float2(fmaf(ax, inv, add), fmaf(ay, inv, add));
        }
    }

    // v = gconv(x, wv), 16 channels for this z
    const int o0 = z * 16;
    const float* wvg = wv + g * 1024 + o0 * 32;
    float* vp = vout + (size_t)(b * 256 + g * 32 + o0) * VS + pix2;
#pragma unroll 4
    for (int o = 0; o < 16; ++o) {
        float ax = 0.f, ay = 0.f;
#pragma unroll
        for (int ci = 0; ci < 32; ++ci) {
            const float w = wvg[o * 32 + ci];
            ax = fmaf(xg[ci].x, w, ax);
            ay = fmaf(xg[ci].y, w, ay);
        }
        *(float2*)(vp + (size_t)o * VS) = make_float2(ax, ay);
    }
}

// ---- k2: softmax attention + 9-tap gather ; 4 px/thread, 8 ch per z --------
__global__ __launch_bounds__(256) void la_k2(
    const float* __restrict__ mn, const float* __restrict__ v,
    float* __restrict__ out)
{
    const int q  = blockIdx.x * blockDim.x + threadIdx.x;  // quad index 0..4095
    const int p4 = q * 4;
    const int bg = blockIdx.y;
    const int b  = bg >> 3, g = bg & 7;
    const int h  = p4 >> 7, w0 = p4 & 127;                 // w0 in {0,4,...,124}

    int rofs[3];
    bool rok[3];
#pragma unroll
    for (int di = 0; di < 3; ++di) {
        const int hh = h + di - 1;
        rok[di]  = ((unsigned)hh < 128u);
        rofs[di] = (rok[di] ? hh : h) * WD;
    }
    const bool lok = (w0 > 0);
    const bool rvk = (w0 + 4 < 128);
    const int  lc  = lok ? (w0 - 1) : w0;
    const int  rc  = rvk ? (w0 + 4) : (w0 + 3);

    // ---- neighbor rows: 6 values per row ----
    const float* nbch = mn + (size_t)(b * 80 + g) * MNS;
    float nrv[3][6];
#pragma unroll
    for (int di = 0; di < 3; ++di) {
        const float* rp = nbch + rofs[di];
        const float4 f4 = *(const float4*)(rp + w0);
        nrv[di][0] = (rok[di] && lok) ? rp[lc] : 0.f;
        nrv[di][1] = rok[di] ? f4.x : 0.f;
        nrv[di][2] = rok[di] ? f4.y : 0.f;
        nrv[di][3] = rok[di] ? f4.z : 0.f;
        nrv[di][4] = rok[di] ? f4.w : 0.f;
        nrv[di][5] = (rok[di] && rvk) ? rp[rc] : 0.f;
    }

    // ---- logits & softmax for 4 pixels ----
    const float* maskp = mn + (size_t)(b * 80 + 8 + g * 9) * MNS + p4;
    float wsel[4][9];
    float mx[4] = {-1e30f, -1e30f, -1e30f, -1e30f};
#pragma unroll
    for (int k = 0; k < 9; ++k) {
        const int di = k / 3, dj = k % 3;
        const float4 mk = *(const float4*)(maskp + (size_t)k * MNS);
        wsel[0][k] = mk.x + nrv[di][0 + dj];
        wsel[1][k] = mk.y + nrv[di][1 + dj];
        wsel[2][k] = mk.z + nrv[di][2 + dj];
        wsel[3][k] = mk.w + nrv[di][3 + dj];
#pragma unroll
        for (int j = 0; j < 4; ++j) mx[j] = fmaxf(mx[j], wsel[j][k]);
    }
#pragma unroll
    for (int j = 0; j < 4; ++j) {
        float s = 0.f;
#pragma unroll
        for (int k = 0; k < 9; ++k) {
            const float e = __expf(wsel[j][k] - mx[j]);
            s += e;
            const int di = k / 3, dj = k % 3;
            const int col = w0 + j + dj - 1;
            const bool ok = rok[di] && ((unsigned)col < 128u);
            wsel[j][k] = ok ? e : 0.f;
        }
        const float rs = 1.f / s;
#pragma unroll
        for (int k = 0; k < 9; ++k) wsel[j][k] *= rs;
    }

    // ---- 8 v-channels for this z-slice ----
    const int o0 = blockIdx.z * 8;
    const float* vg = v   + (size_t)(b * 256 + g * 32 + o0) * VS;
    float*       og = out + (size_t)(b * 256 + g * 32 + o0) * HW + p4;
#pragma unroll
    for (int o = 0; o < 8; ++o) {
        const float* vo = vg + (size_t)o * VS;
        float vrv[3][6];
#pragma unroll
        for (int di = 0; di < 3; ++di) {
            const float* rp = vo + rofs[di];
            const float4 f4 = *(const float4*)(rp + w0);
            vrv[di][0] = rp[lc];
            vrv[di][1] = f4.x; vrv[di][2] = f4.y; vrv[di][3] = f4.z; vrv[di][4] = f4.w;
            vrv[di][5] = rp[rc];
        }
        float acc[4] = {0.f, 0.f, 0.f, 0.f};
#pragma unroll
        for (int k = 0; k < 9; ++k) {
            const int di = k / 3, dj = k % 3;
#pragma unroll
            for (int j = 0; j < 4; ++j)
                acc[j] = fmaf(wsel[j][k], vrv[di][j + dj], acc[j]);
        }
        *(float4*)(og + (size_t)o * HW) = make_float4(acc[0], acc[1], acc[2], acc[3]);
    }
}

extern "C" void kernel_launch(void* const* d_in, const int* in_sizes, int n_in,
                              void* d_out, int out_size, void* d_ws, size_t ws_size,
                              hipStream_t stream)
{
    const float* x   = (const float*)d_in[0];
    const float* w1  = (const float*)d_in[1];
    const float* b1  = (const float*)d_in[2];
    const float* g1  = (const float*)d_in[3];
    const float* be1 = (const float*)d_in[4];
    const float* m1  = (const float*)d_in[5];
    const float* v1  = (const float*)d_in[6];
    const float* w2  = (const float*)d_in[7];
    const float* b2  = (const float*)d_in[8];
    const float* g2  = (const float*)d_in[9];
    const float* be2 = (const float*)d_in[10];
    const float* m2  = (const float*)d_in[11];
    const float* v2  = (const float*)d_in[12];
    const float* wv  = (const float*)d_in[13];

    float* out = (float*)d_out;
    float* mn  = (float*)d_ws;                         // 2*80*MNS floats
    float* v   = mn + (size_t)2 * 80 * MNS;            // 2*256*MNS floats

    dim3 blk(256);
    dim3 g1d(HW / 512, 16, 2);     // 2 px/thread, v split in halves -> 1024 blocks
    dim3 g2d(HW / 1024, 16, 4);    // 4 px/thread, 8 ch per z        -> 1024 blocks

    hipLaunchKernelGGL(la_k1, g1d, blk, 0, stream,
                       x, w1, b1, g1, be1, m1, v1, w2, b2, g2, be2, m2, v2, wv,
                       mn, v);
    hipLaunchKernelGGL(la_k2, g2d, blk, 0, stream, mn, v, out);
}